// Round 7
// baseline (433.077 us; speedup 1.0000x reference)
//
#include <hip/hip_runtime.h>
#include <stdint.h>

#define BATCH 512
#define SEQ   256
#define EMBD  64
#define HID   128
#define GATES 512
#define NST   18
#define LROW  (BATCH * NST)   /* 9216 floats per time slice */

typedef short  bf16x8 __attribute__((ext_vector_type(8)));
typedef float  f32x4  __attribute__((ext_vector_type(4)));

__device__ __forceinline__ short f2bf(float f) {
  unsigned u = __float_as_uint(f);
  u = (u + 0x7FFFu + ((u >> 16) & 1u)) >> 16;
  return (short)u;
}
__device__ __forceinline__ float rcpf(float x) { return __builtin_amdgcn_rcpf(x); }

// lgkm-only barrier (vmem ops stay in flight across it).
__device__ __forceinline__ void lds_barrier() {
  __builtin_amdgcn_sched_barrier(0);
  asm volatile("s_waitcnt lgkmcnt(0)");
  __builtin_amdgcn_s_barrier();
  __builtin_amdgcn_sched_barrier(0);
}

// ---------------- K1: embedding gather, time-major bf16 ----------------
__global__ void k_embed(const int* __restrict__ inputs, const float* __restrict__ E,
                        short* __restrict__ emb) {
  int tid = blockIdx.x * 256 + threadIdx.x;   // 2^21 threads total
  int e4 = (tid & 15) << 2;
  int b  = (tid >> 4) & (BATCH - 1);
  int t  = tid >> 13;
  int vid = inputs[b * SEQ + t];
  float4 v = *reinterpret_cast<const float4*>(E + (size_t)vid * EMBD + e4);
  short4 o;
  o.x = f2bf(v.x); o.y = f2bf(v.y); o.z = f2bf(v.z); o.w = f2bf(v.w);
  *reinterpret_cast<short4*>(emb + (size_t)(t * BATCH + b) * EMBD + e4) = o;
}

// ---------------- K2: bidirectional LSTM + fused logits ----------------
// 64 blocks (1/CU): even=forward, odd=backward; block owns 16 batch rows.
// 8 waves; wave w owns hidden cols [16w,16w+16) across all 4 gates.
// amdgpu_waves_per_eu(2,2): grid is 64 blocks -> exactly 1 block/CU =
// 2 waves/SIMD. Pinning this raises the allocator budget to 256 arch
// VGPRs/wave; without it the compiler targets 128 and parks the ~116
// register-resident weights in AGPRs, paying v_accvgpr_read/write in the
// serial chain every step (R1-R6: VGPR_Count=128, 2600 cyc/step).
__global__ void __launch_bounds__(512)
__attribute__((amdgpu_waves_per_eu(2, 2)))
k_lstm(const short* __restrict__ emb,
       const float* __restrict__ Wx_f, const float* __restrict__ Wh_f, const float* __restrict__ b_f,
       const float* __restrict__ Wx_b, const float* __restrict__ Wh_b, const float* __restrict__ b_b,
       const float* __restrict__ Wd,
       float* __restrict__ logits_f, float* __restrict__ logits_b) {
  const int blk  = blockIdx.x;
  const int dir  = blk & 1;
  const int b0   = (blk >> 1) * 16;
  const int tid  = threadIdx.x;
  const int w    = tid >> 6;
  const int lane = tid & 63;
  const int quad = lane >> 4;      // 0..3
  const int mrow = lane & 15;      // A-frag row / C-frag col
  const int m0   = quad * 4;       // C-frag rows m0..m0+3
  const int hcol = w * 16 + mrow;  // hidden col this lane owns (0..127)

  const float* WX = dir ? Wx_b : Wx_f;
  const float* WH = dir ? Wh_b : Wh_f;
  const float* BV = dir ? b_b  : b_f;
  float* LOG = dir ? logits_b : logits_f;

  // ---- load weights into register B-fragments (one-time) ----
  bf16x8 wxf[4][2], whf[4][4], wdf[4];
  float bias[4];
#pragma unroll
  for (int q = 0; q < 4; ++q) {
    int col = q * HID + hcol;
    bias[q] = BV[col];
#pragma unroll
    for (int kt = 0; kt < 2; ++kt) {
      bf16x8 f;
#pragma unroll
      for (int j = 0; j < 8; ++j) {
        int k = kt * 32 + quad * 8 + j;
        f[j] = f2bf(WX[k * GATES + col]);
      }
      wxf[q][kt] = f;
    }
#pragma unroll
    for (int kt = 0; kt < 4; ++kt) {
      bf16x8 f;
#pragma unroll
      for (int j = 0; j < 8; ++j) {
        int k = kt * 32 + quad * 8 + j;
        f[j] = f2bf(WH[k * GATES + col]);
      }
      whf[q][kt] = f;
    }
  }
  const int  lcol = w * 16 + mrow;
  const bool lval = (w < 2) && (lcol < NST);
#pragma unroll
  for (int kt = 0; kt < 4; ++kt) {
    bf16x8 f;
#pragma unroll
    for (int j = 0; j < 8; ++j) {
      int k = kt * 32 + quad * 8 + j;
      f[j] = lval ? f2bf(Wd[(dir * HID + k) * NST + lcol]) : (short)0;
    }
    wdf[kt] = f;
  }

  // ---- LDS: double-buffered swizzled h tile [16 rows][128 cols] bf16 ----
  __shared__ __align__(16) short hbuf[2][16 * 128];
  {
    int4* p = reinterpret_cast<int4*>(hbuf);
    int4 z; z.x = 0; z.y = 0; z.z = 0; z.w = 0;
    p[tid] = z;   // 512 * 16B == 8192B
  }
  __syncthreads();

  float c[4] = {0.f, 0.f, 0.f, 0.f};
  f32x4 la[8];
#pragma unroll
  for (int i = 0; i < 8; ++i) { la[i][0]=0.f; la[i][1]=0.f; la[i][2]=0.f; la[i][3]=0.f; }

  const int t0 = dir ? (SEQ - 1) : 0;
  const short* efp0 = emb + ((size_t)(t0 * BATCH + b0 + mrow) * EMBD + quad * 8);
  bf16x8 xa0 = *reinterpret_cast<const bf16x8*>(efp0);
  bf16x8 xa1 = *reinterpret_cast<const bf16x8*>(efp0 + 32);

  for (int so = 0; so < SEQ; so += 8) {
#pragma unroll
    for (int si = 0; si < 8; ++si) {
      const int s = so + si;
      const int p = s & 1;
      // prefetch next x fragments
      const int sn = (s + 1 < SEQ) ? s + 1 : s;
      const int tn = dir ? (SEQ - 1 - sn) : sn;
      const short* efp = emb + ((size_t)(tn * BATCH + b0 + mrow) * EMBD + quad * 8);
      bf16x8 xb0 = *reinterpret_cast<const bf16x8*>(efp);
      bf16x8 xb1 = *reinterpret_cast<const bf16x8*>(efp + 32);

      // h_{s-1} A-fragments from previous buffer (swizzled ds_read_b128)
      bf16x8 hfr[4];
      const char* hb = reinterpret_cast<const char*>(hbuf[p ^ 1]);
#pragma unroll
      for (int kt = 0; kt < 4; ++kt) {
        unsigned off = (unsigned)((mrow * 128 + kt * 32 + quad * 8) * 2) ^ ((unsigned)(mrow & 7) << 4);
        hfr[kt] = *reinterpret_cast<const bf16x8*>(hb + off);
      }

      // z = bias + x@Wx + h@Wh ; two independent 3-deep chains per gate
      f32x4 za[4], zb[4];
#pragma unroll
      for (int q = 0; q < 4; ++q) {
        f32x4 a = {bias[q], bias[q], bias[q], bias[q]};
        a = __builtin_amdgcn_mfma_f32_16x16x32_bf16(xa0, wxf[q][0], a, 0, 0, 0);
        f32x4 b2 = {0.f, 0.f, 0.f, 0.f};
        b2 = __builtin_amdgcn_mfma_f32_16x16x32_bf16(xa1, wxf[q][1], b2, 0, 0, 0);
        a  = __builtin_amdgcn_mfma_f32_16x16x32_bf16(hfr[0], whf[q][0], a, 0, 0, 0);
        b2 = __builtin_amdgcn_mfma_f32_16x16x32_bf16(hfr[2], whf[q][2], b2, 0, 0, 0);
        a  = __builtin_amdgcn_mfma_f32_16x16x32_bf16(hfr[1], whf[q][1], a, 0, 0, 0);
        b2 = __builtin_amdgcn_mfma_f32_16x16x32_bf16(hfr[3], whf[q][3], b2, 0, 0, 0);
        za[q] = a; zb[q] = b2;
      }

      // gates (Keras order i,f,g,o); fused sigma*tanh: 5 exp + 3 rcp per elem
      short hv[4];
#pragma unroll
      for (int r = 0; r < 4; ++r) {
        float zi = za[0][r] + zb[0][r];
        float zf = za[1][r] + zb[1][r];
        float zg = za[2][r] + zb[2][r];
        float zo = za[3][r] + zb[3][r];
        float ei  = __expf(-zi);
        float e2g = __expf(-2.f * zg);
        float ef  = __expf(-zf);
        float fg  = rcpf(1.f + ef);
        float it  = (1.f - e2g) * rcpf((1.f + ei) * (1.f + e2g));  // sig(i)*tanh(g)
        float cn  = fg * c[r] + it;
        c[r] = cn;
        float eo  = __expf(-zo);
        float e2c = __expf(-2.f * cn);
        hv[r] = f2bf((1.f - e2c) * rcpf((1.f + eo) * (1.f + e2c)));  // sig(o)*tanh(c)
      }

      // write h_s (swizzled b16 stores)
      char* wb = reinterpret_cast<char*>(hbuf[p]);
#pragma unroll
      for (int r = 0; r < 4; ++r) {
        int m = m0 + r;
        unsigned off = (unsigned)((m * 128 + hcol) * 2) ^ ((unsigned)(m & 7) << 4);
        *reinterpret_cast<short*>(wb + off) = hv[r];
      }

      // fused logits for h_{s-1} -> REGISTER slot (no global store here)
      if (w < 2 && (so + si) > 0) {
        f32x4 l = {0.f, 0.f, 0.f, 0.f};
#pragma unroll
        for (int kt = 0; kt < 4; ++kt)
          l = __builtin_amdgcn_mfma_f32_16x16x32_bf16(hfr[kt], wdf[kt], l, 0, 0, 0);
        la[si] = l;
      }

      lds_barrier();   // lgkm-only; x loads stay in flight
      xa0 = xb0; xa1 = xb1;
    }

    // flush 8 logit slots (positions so+si-1); once per 8 steps the vmcnt
    // path eats the store-acks, instead of every step
    if (lval) {
#pragma unroll
      for (int si = 0; si < 8; ++si) {
        if (so == 0 && si == 0) continue;
        int pos = dir ? (SEQ - so - si) : (so + si - 1);
        float* dst = LOG + (size_t)pos * LROW + (size_t)(b0 + m0) * NST + lcol;
        dst[0]       = la[si][0];
        dst[NST]     = la[si][1];
        dst[2 * NST] = la[si][2];
        dst[3 * NST] = la[si][3];
      }
    }
  }

  // final logits for h_{SEQ-1}
  if (w < 2) {
    const char* hb = reinterpret_cast<const char*>(hbuf[(SEQ - 1) & 1]);
    bf16x8 hfr[4];
#pragma unroll
    for (int kt = 0; kt < 4; ++kt) {
      unsigned off = (unsigned)((mrow * 128 + kt * 32 + quad * 8) * 2) ^ ((unsigned)(mrow & 7) << 4);
      hfr[kt] = *reinterpret_cast<const bf16x8*>(hb + off);
    }
    f32x4 l = {0.f, 0.f, 0.f, 0.f};
#pragma unroll
    for (int kt = 0; kt < 4; ++kt)
      l = __builtin_amdgcn_mfma_f32_16x16x32_bf16(hfr[kt], wdf[kt], l, 0, 0, 0);
    int tp = dir ? 0 : (SEQ - 1);
    if (lval) {
      float* dst = LOG + (size_t)tp * LROW + (size_t)(b0 + m0) * NST + lcol;
#pragma unroll
      for (int r = 0; r < 4; ++r) dst[r * NST] = l[r];
    }
  }
}

// ---------------- K2.5: lsum = logits_f + logits_b + bd (pre-sum) ----------------
// Halves k_crf's per-step serial loads (1 instead of 2) and removes the bd add.
__global__ void k_sum(const float* __restrict__ lf, const float* __restrict__ lb,
                      const float* __restrict__ bd, float* __restrict__ lsum) {
  int i = (blockIdx.x * 256 + threadIdx.x) * 4;   // 2304 blocks x 256 thr x 4
  float4 a = *reinterpret_cast<const float4*>(lf + i);
  float4 b = *reinterpret_cast<const float4*>(lb + i);
  int j = i % NST;
  float4 o;
  o.x = a.x + b.x + bd[j];
  o.y = a.y + b.y + bd[(j + 1) % NST];
  o.z = a.z + b.z + bd[(j + 2) % NST];
  o.w = a.w + b.w + bd[(j + 3) % NST];
  *reinterpret_cast<float4*>(lsum + i) = o;
}

// ---------------- K3: CRF log-likelihood, one wave per batch row ----------------
// 128 blocks x 4 waves: one wave on every SIMD of 128 CUs. 8-deep raw-load
// prefetch ring over lsum (single load per serial step).
__global__ void k_crf(const float* __restrict__ ls, const float* __restrict__ Tm,
                      const int* __restrict__ labels, float* __restrict__ out) {
  const int wv   = threadIdx.x >> 6;
  const int lane = threadIdx.x & 63;
  const int b    = blockIdx.x * 4 + wv;
  __shared__ unsigned char lab[4][SEQ];

  // labels row -> LDS bytes; length = count(label != 0)
  int4 lv = *reinterpret_cast<const int4*>(labels + (size_t)b * SEQ + lane * 4);
  uchar4 lc;
  lc.x = (unsigned char)lv.x; lc.y = (unsigned char)lv.y;
  lc.z = (unsigned char)lv.z; lc.w = (unsigned char)lv.w;
  *reinterpret_cast<uchar4*>(&lab[wv][lane * 4]) = lc;
  int cnt = (lv.x != 0) + (lv.y != 0) + (lv.z != 0) + (lv.w != 0);
#pragma unroll
  for (int d = 32; d; d >>= 1) cnt += __shfl_xor(cnt, d);
  const int len = cnt;

  // unary + binary (lsum already includes bd)
  float ub = 0.f;
#pragma unroll
  for (int ii = 0; ii < 4; ++ii) {
    int p = ii * 64 + lane;
    int lp = lab[wv][p];
    if (p < len) ub += ls[(size_t)p * LROW + (size_t)b * NST + lp];
    if (p < SEQ - 1 && (p + 1) < len)
      ub += Tm[lp * NST + lab[wv][p + 1]];
  }
#pragma unroll
  for (int d = 32; d; d >>= 1) ub += __shfl_xor(ub, d);

  // forward algorithm. h9 = lane>>5 (9-state half), j = lane&31 (state).
  const int h9 = lane >> 5;
  const int j  = lane & 31;
  const int jj = (j < NST) ? j : 0;
  float Tcol[9];
#pragma unroll
  for (int i2 = 0; i2 < 9; ++i2) Tcol[i2] = Tm[(9 * h9 + i2) * NST + jj];
  const size_t rowoff = (size_t)b * NST + jj;

  float alpha = ls[rowoff];  // t = 0

  // prefetch ring: pf[u] holds lsum for step t (consumed 8 steps later)
  float pf[8];
#pragma unroll
  for (int u = 0; u < 8; ++u) pf[u] = ls[(size_t)(1 + u) * LROW + rowoff];

  for (int tb = 1; tb < len; tb += 8) {
#pragma unroll
    for (int u = 0; u < 8; ++u) {
      int t = tb + u;
      if (t < len) {
        float lg = pf[u];
        float tt[9];
#pragma unroll
        for (int i2 = 0; i2 < 9; ++i2)
          tt[i2] = __shfl(alpha, 9 * h9 + i2) + Tcol[i2];
        float ma = fmaxf(fmaxf(tt[0], tt[1]), fmaxf(tt[2], tt[3]));
        float mb = fmaxf(fmaxf(tt[4], tt[5]), fmaxf(tt[6], tt[7]));
        float m9 = fmaxf(fmaxf(ma, mb), tt[8]);
        float s0 = __expf(tt[0] - m9) + __expf(tt[1] - m9);
        float s1 = __expf(tt[2] - m9) + __expf(tt[3] - m9);
        float s2 = __expf(tt[4] - m9) + __expf(tt[5] - m9);
        float s3 = __expf(tt[6] - m9) + __expf(tt[7] - m9);
        float s9 = ((s0 + s1) + (s2 + s3)) + __expf(tt[8] - m9);
        float mo = __shfl_xor(m9, 32);
        float so = __shfl_xor(s9, 32);
        float m  = fmaxf(m9, mo);
        float s  = s9 * __expf(m9 - m) + so * __expf(mo - m);
        alpha = m + __logf(s) + lg;
      }
      int tn = t + 8; if (tn > SEQ - 1) tn = SEQ - 1;   // always in-bounds
      pf[u] = ls[(size_t)tn * LROW + rowoff];
    }
  }

  // log_norm = LSE over states; reduce across lanes (lanes 0..17 valid)
  float v = (lane < NST) ? alpha : -1e30f;
  float mm = v;
#pragma unroll
  for (int d = 32; d; d >>= 1) mm = fmaxf(mm, __shfl_xor(mm, d));
  float e = (lane < NST) ? __expf(alpha - mm) : 0.f;
#pragma unroll
  for (int d = 32; d; d >>= 1) e += __shfl_xor(e, d);
  if (lane == 0) out[b] = ub - (mm + __logf(e));
}

// ---------------- K4: T passthrough (second tuple output) ----------------
__global__ void k_tcopy(const float* __restrict__ Tm, float* __restrict__ out) {
  int i = blockIdx.x * 256 + threadIdx.x;
  if (i < NST * NST) out[BATCH + i] = Tm[i];
}

extern "C" void kernel_launch(void* const* d_in, const int* in_sizes, int n_in,
                              void* d_out, int out_size, void* d_ws, size_t ws_size,
                              hipStream_t stream) {
  const int*   inputs = (const int*)d_in[0];
  const int*   labels = (const int*)d_in[1];
  const float* E      = (const float*)d_in[2];
  const float* Wx_f   = (const float*)d_in[3];
  const float* Wh_f   = (const float*)d_in[4];
  const float* b_f    = (const float*)d_in[5];
  const float* Wx_b   = (const float*)d_in[6];
  const float* Wh_b   = (const float*)d_in[7];
  const float* b_b    = (const float*)d_in[8];
  const float* Wd     = (const float*)d_in[9];
  const float* bd     = (const float*)d_in[10];
  const float* Tm     = (const float*)d_in[11];
  float* out = (float*)d_out;

  char* ws = (char*)d_ws;
  short* emb      = (short*)ws;                                  // 16,777,216 B (dead after k_lstm)
  float* lsum     = (float*)ws;                                  // reuses emb region (9,437,184 B)
  float* logits_f = (float*)(ws + (size_t)16777216);             //  9,437,184 B
  float* logits_b = (float*)(ws + (size_t)16777216 + 9437184);   //  9,437,184 B

  k_embed<<<8192, 256, 0, stream>>>(inputs, E, emb);
  k_lstm<<<64, 512, 0, stream>>>(emb, Wx_f, Wh_f, b_f, Wx_b, Wh_b, b_b, Wd,
                                 logits_f, logits_b);
  k_sum<<<2304, 256, 0, stream>>>(logits_f, logits_b, bd, lsum);
  k_crf<<<128, 256, 0, stream>>>(lsum, Tm, labels, out);
  k_tcopy<<<2, 256, 0, stream>>>(Tm, out);
}

// Round 8
// 394.764 us; speedup vs baseline: 1.0971x; 1.0971x over previous
//
#include <hip/hip_runtime.h>
#include <stdint.h>

#define BATCH 512
#define SEQ   256
#define EMBD  64
#define HID   128
#define GATES 512
#define NST   18
#define LROW  (BATCH * NST)   /* 9216 floats per time slice */

typedef short  bf16x8 __attribute__((ext_vector_type(8)));
typedef float  f32x4  __attribute__((ext_vector_type(4)));

__device__ __forceinline__ short f2bf(float f) {
  unsigned u = __float_as_uint(f);
  u = (u + 0x7FFFu + ((u >> 16) & 1u)) >> 16;
  return (short)u;
}
__device__ __forceinline__ float rcpf(float x) { return __builtin_amdgcn_rcpf(x); }

// lgkm-only barrier (vmem ops stay in flight across it).
__device__ __forceinline__ void lds_barrier() {
  __builtin_amdgcn_sched_barrier(0);
  asm volatile("s_waitcnt lgkmcnt(0)");
  __builtin_amdgcn_s_barrier();
  __builtin_amdgcn_sched_barrier(0);
}

// ---------------- K1: embedding gather, time-major bf16 ----------------
__global__ void k_embed(const int* __restrict__ inputs, const float* __restrict__ E,
                        short* __restrict__ emb) {
  int tid = blockIdx.x * 256 + threadIdx.x;   // 2^21 threads total
  int e4 = (tid & 15) << 2;
  int b  = (tid >> 4) & (BATCH - 1);
  int t  = tid >> 13;
  int vid = inputs[b * SEQ + t];
  float4 v = *reinterpret_cast<const float4*>(E + (size_t)vid * EMBD + e4);
  short4 o;
  o.x = f2bf(v.x); o.y = f2bf(v.y); o.z = f2bf(v.z); o.w = f2bf(v.w);
  *reinterpret_cast<short4*>(emb + (size_t)(t * BATCH + b) * EMBD + e4) = o;
}

// ---------------- K2: bidirectional LSTM + fused logits ----------------
// R7 post-mortem: active-CU VALUBusy ~60% -> issue-bound on the gate epilogue,
// not latency. This version: 128 blocks (2x CUs), R=8 batch rows per block.
// MFMA M=16 tile is half-garbage (MFMA pipe only ~31% busy - free), and the
// epilogue is redistributed across ALL 64 lanes via __shfl_up(.,32): lanes
// 0-31 keep acc regs 0,1 (rows m0,m0+1), lanes 32-63 take regs 2,3 of lane-32
// (rows m0+2,m0+3) -> 2 elems/lane (was 4), halving per-wave trans/VALU issue.
// h-LDS rows 8-15 stay zero forever, confining all garbage to C rows 8-15.
__global__ void __launch_bounds__(512)
__attribute__((amdgpu_waves_per_eu(2, 2)))
k_lstm(const short* __restrict__ emb,
       const float* __restrict__ Wx_f, const float* __restrict__ Wh_f, const float* __restrict__ b_f,
       const float* __restrict__ Wx_b, const float* __restrict__ Wh_b, const float* __restrict__ b_b,
       const float* __restrict__ Wd,
       float* __restrict__ logits_f, float* __restrict__ logits_b) {
  const int blk  = blockIdx.x;
  const int dir  = blk & 1;
  const int b0   = (blk >> 1) * 8;          // 8 batch rows per block
  const int tid  = threadIdx.x;
  const int w    = tid >> 6;
  const int lane = tid & 63;
  const int quad = lane >> 4;      // 0..3
  const int mrow = lane & 15;      // A-frag row / C-frag col
  const int m0   = quad * 4;       // C-frag rows m0..m0+3
  const int hcol = w * 16 + mrow;  // hidden col this lane owns (0..127)
  const bool hi32 = (lane >= 32);
  const int erow = (b0 + mrow < BATCH) ? (b0 + mrow) : (BATCH - 1);  // clamp tail

  const float* WX = dir ? Wx_b : Wx_f;
  const float* WH = dir ? Wh_b : Wh_f;
  const float* BV = dir ? b_b  : b_f;
  float* LOG = dir ? logits_b : logits_f;

  // ---- load weights into register B-fragments (one-time) ----
  bf16x8 wxf[4][2], whf[4][4], wdf[4];
  float bias[4];
#pragma unroll
  for (int q = 0; q < 4; ++q) {
    int col = q * HID + hcol;
    bias[q] = BV[col];
#pragma unroll
    for (int kt = 0; kt < 2; ++kt) {
      bf16x8 f;
#pragma unroll
      for (int j = 0; j < 8; ++j) {
        int k = kt * 32 + quad * 8 + j;
        f[j] = f2bf(WX[k * GATES + col]);
      }
      wxf[q][kt] = f;
    }
#pragma unroll
    for (int kt = 0; kt < 4; ++kt) {
      bf16x8 f;
#pragma unroll
      for (int j = 0; j < 8; ++j) {
        int k = kt * 32 + quad * 8 + j;
        f[j] = f2bf(WH[k * GATES + col]);
      }
      whf[q][kt] = f;
    }
  }
  const int  lcol = w * 16 + mrow;
  // logits store mask: waves 0-1, class col < 18, batch rows valid (quads 0-1)
  const bool lval = (w < 2) && (lcol < NST) && (quad < 2);
#pragma unroll
  for (int kt = 0; kt < 4; ++kt) {
    bf16x8 f;
#pragma unroll
    for (int j = 0; j < 8; ++j) {
      int k = kt * 32 + quad * 8 + j;
      f[j] = (w < 2 && lcol < NST) ? f2bf(Wd[(dir * HID + k) * NST + lcol]) : (short)0;
    }
    wdf[kt] = f;
  }

  // ---- LDS: double-buffered swizzled h tile [16 rows][128 cols] bf16 ----
  // Rows 8-15 are zeroed once and NEVER rewritten (R=8): A-frag rows 8-15
  // read zeros -> garbage confined to unused C rows.
  __shared__ __align__(16) short hbuf[2][16 * 128];
  {
    int4* p = reinterpret_cast<int4*>(hbuf);
    int4 z; z.x = 0; z.y = 0; z.z = 0; z.w = 0;
    p[tid] = z;   // 512 * 16B == 8192B
  }
  __syncthreads();

  float c[2] = {0.f, 0.f};
  f32x4 la[8];
#pragma unroll
  for (int i = 0; i < 8; ++i) { la[i][0]=0.f; la[i][1]=0.f; la[i][2]=0.f; la[i][3]=0.f; }

  const int t0 = dir ? (SEQ - 1) : 0;
  const short* efp0 = emb + ((size_t)(t0 * BATCH + erow) * EMBD + quad * 8);
  bf16x8 xa0 = *reinterpret_cast<const bf16x8*>(efp0);
  bf16x8 xa1 = *reinterpret_cast<const bf16x8*>(efp0 + 32);

  for (int so = 0; so < SEQ; so += 8) {
#pragma unroll
    for (int si = 0; si < 8; ++si) {
      const int s = so + si;
      const int p = s & 1;
      // prefetch next x fragments
      const int sn = (s + 1 < SEQ) ? s + 1 : s;
      const int tn = dir ? (SEQ - 1 - sn) : sn;
      const short* efp = emb + ((size_t)(tn * BATCH + erow) * EMBD + quad * 8);
      bf16x8 xb0 = *reinterpret_cast<const bf16x8*>(efp);
      bf16x8 xb1 = *reinterpret_cast<const bf16x8*>(efp + 32);

      // h_{s-1} A-fragments from previous buffer (swizzled ds_read_b128)
      bf16x8 hfr[4];
      const char* hb = reinterpret_cast<const char*>(hbuf[p ^ 1]);
#pragma unroll
      for (int kt = 0; kt < 4; ++kt) {
        unsigned off = (unsigned)((mrow * 128 + kt * 32 + quad * 8) * 2) ^ ((unsigned)(mrow & 7) << 4);
        hfr[kt] = *reinterpret_cast<const bf16x8*>(hb + off);
      }

      // z = bias + x@Wx + h@Wh ; two independent 3-deep chains per gate
      f32x4 za[4], zb[4];
#pragma unroll
      for (int q = 0; q < 4; ++q) {
        f32x4 a = {bias[q], bias[q], bias[q], bias[q]};
        a = __builtin_amdgcn_mfma_f32_16x16x32_bf16(xa0, wxf[q][0], a, 0, 0, 0);
        f32x4 b2 = {0.f, 0.f, 0.f, 0.f};
        b2 = __builtin_amdgcn_mfma_f32_16x16x32_bf16(xa1, wxf[q][1], b2, 0, 0, 0);
        a  = __builtin_amdgcn_mfma_f32_16x16x32_bf16(hfr[0], whf[q][0], a, 0, 0, 0);
        b2 = __builtin_amdgcn_mfma_f32_16x16x32_bf16(hfr[2], whf[q][2], b2, 0, 0, 0);
        a  = __builtin_amdgcn_mfma_f32_16x16x32_bf16(hfr[1], whf[q][1], a, 0, 0, 0);
        b2 = __builtin_amdgcn_mfma_f32_16x16x32_bf16(hfr[3], whf[q][3], b2, 0, 0, 0);
        za[q] = a; zb[q] = b2;
      }

      // redistribute: lanes 32-63 take acc regs 2,3 from lane-32 so all 64
      // lanes process 2 valid elements (rows: q01 -> m0,m0+1 ; q23 -> m0'+2,3)
      float zsel[4][2];
#pragma unroll
      for (int q = 0; q < 4; ++q) {
        float z2 = za[q][2] + zb[q][2];
        float z3 = za[q][3] + zb[q][3];
        float u2 = __shfl_up(z2, 32, 64);
        float u3 = __shfl_up(z3, 32, 64);
        float z0 = za[q][0] + zb[q][0];
        float z1 = za[q][1] + zb[q][1];
        zsel[q][0] = hi32 ? u2 : z0;
        zsel[q][1] = hi32 ? u3 : z1;
      }

      // gates (Keras order i,f,g,o); fused sigma*tanh: 2 elems/lane
      const int rbase = ((quad & 1) << 2) + (hi32 ? 2 : 0);
      char* wb = reinterpret_cast<char*>(hbuf[p]);
#pragma unroll
      for (int rr = 0; rr < 2; ++rr) {
        float zi = zsel[0][rr];
        float zf = zsel[1][rr];
        float zg = zsel[2][rr];
        float zo = zsel[3][rr];
        float ei  = __expf(-zi);
        float e2g = __expf(-2.f * zg);
        float ef  = __expf(-zf);
        float fg  = rcpf(1.f + ef);
        float it  = (1.f - e2g) * rcpf((1.f + ei) * (1.f + e2g));  // sig(i)*tanh(g)
        float cn  = fg * c[rr] + it;
        c[rr] = cn;
        float eo  = __expf(-zo);
        float e2c = __expf(-2.f * cn);
        short hv = f2bf((1.f - e2c) * rcpf((1.f + eo) * (1.f + e2c)));  // sig(o)*tanh(c)
        int m = rbase + rr;
        unsigned off = (unsigned)((m * 128 + hcol) * 2) ^ ((unsigned)(m & 7) << 4);
        *reinterpret_cast<short*>(wb + off) = hv;
      }

      // fused logits for h_{s-1} -> REGISTER slot (no global store here)
      if (w < 2 && (so + si) > 0) {
        f32x4 l = {0.f, 0.f, 0.f, 0.f};
#pragma unroll
        for (int kt = 0; kt < 4; ++kt)
          l = __builtin_amdgcn_mfma_f32_16x16x32_bf16(hfr[kt], wdf[kt], l, 0, 0, 0);
        la[si] = l;
      }

      lds_barrier();   // lgkm-only; x loads stay in flight
      xa0 = xb0; xa1 = xb1;
    }

    // flush 8 logit slots (positions so+si-1); vmcnt pays store-acks once
    // per 8 steps instead of every step
    if (lval) {
#pragma unroll
      for (int si = 0; si < 8; ++si) {
        if (so == 0 && si == 0) continue;
        int pos = dir ? (SEQ - so - si) : (so + si - 1);
        float* dst = LOG + (size_t)pos * LROW + (size_t)(b0 + m0) * NST + lcol;
        dst[0]       = la[si][0];
        dst[NST]     = la[si][1];
        dst[2 * NST] = la[si][2];
        dst[3 * NST] = la[si][3];
      }
    }
  }

  // final logits for h_{SEQ-1}
  if (w < 2) {
    const char* hb = reinterpret_cast<const char*>(hbuf[(SEQ - 1) & 1]);
    bf16x8 hfr[4];
#pragma unroll
    for (int kt = 0; kt < 4; ++kt) {
      unsigned off = (unsigned)((mrow * 128 + kt * 32 + quad * 8) * 2) ^ ((unsigned)(mrow & 7) << 4);
      hfr[kt] = *reinterpret_cast<const bf16x8*>(hb + off);
    }
    f32x4 l = {0.f, 0.f, 0.f, 0.f};
#pragma unroll
    for (int kt = 0; kt < 4; ++kt)
      l = __builtin_amdgcn_mfma_f32_16x16x32_bf16(hfr[kt], wdf[kt], l, 0, 0, 0);
    int tp = dir ? 0 : (SEQ - 1);
    if (lval) {
      float* dst = LOG + (size_t)tp * LROW + (size_t)(b0 + m0) * NST + lcol;
#pragma unroll
      for (int r = 0; r < 4; ++r) dst[r * NST] = l[r];
    }
  }
}

// ---------------- K2.5: lsum = logits_f + logits_b + bd (pre-sum) ----------------
__global__ void k_sum(const float* __restrict__ lf, const float* __restrict__ lb,
                      const float* __restrict__ bd, float* __restrict__ lsum) {
  int i = (blockIdx.x * 256 + threadIdx.x) * 4;   // 2304 blocks x 256 thr x 4
  float4 a = *reinterpret_cast<const float4*>(lf + i);
  float4 b = *reinterpret_cast<const float4*>(lb + i);
  int j = i % NST;
  float4 o;
  o.x = a.x + b.x + bd[j];
  o.y = a.y + b.y + bd[(j + 1) % NST];
  o.z = a.z + b.z + bd[(j + 2) % NST];
  o.w = a.w + b.w + bd[(j + 3) % NST];
  *reinterpret_cast<float4*>(lsum + i) = o;
}

// ---------------- K3: CRF log-likelihood, one wave per batch row ----------------
// 128 blocks x 4 waves; 8-deep raw-load prefetch ring over lsum.
__global__ void k_crf(const float* __restrict__ ls, const float* __restrict__ Tm,
                      const int* __restrict__ labels, float* __restrict__ out) {
  const int wv   = threadIdx.x >> 6;
  const int lane = threadIdx.x & 63;
  const int b    = blockIdx.x * 4 + wv;
  __shared__ unsigned char lab[4][SEQ];

  // labels row -> LDS bytes; length = count(label != 0)
  int4 lv = *reinterpret_cast<const int4*>(labels + (size_t)b * SEQ + lane * 4);
  uchar4 lc;
  lc.x = (unsigned char)lv.x; lc.y = (unsigned char)lv.y;
  lc.z = (unsigned char)lv.z; lc.w = (unsigned char)lv.w;
  *reinterpret_cast<uchar4*>(&lab[wv][lane * 4]) = lc;
  int cnt = (lv.x != 0) + (lv.y != 0) + (lv.z != 0) + (lv.w != 0);
#pragma unroll
  for (int d = 32; d; d >>= 1) cnt += __shfl_xor(cnt, d);
  const int len = cnt;

  // unary + binary (lsum already includes bd)
  float ub = 0.f;
#pragma unroll
  for (int ii = 0; ii < 4; ++ii) {
    int p = ii * 64 + lane;
    int lp = lab[wv][p];
    if (p < len) ub += ls[(size_t)p * LROW + (size_t)b * NST + lp];
    if (p < SEQ - 1 && (p + 1) < len)
      ub += Tm[lp * NST + lab[wv][p + 1]];
  }
#pragma unroll
  for (int d = 32; d; d >>= 1) ub += __shfl_xor(ub, d);

  // forward algorithm. h9 = lane>>5 (9-state half), j = lane&31 (state).
  const int h9 = lane >> 5;
  const int j  = lane & 31;
  const int jj = (j < NST) ? j : 0;
  float Tcol[9];
#pragma unroll
  for (int i2 = 0; i2 < 9; ++i2) Tcol[i2] = Tm[(9 * h9 + i2) * NST + jj];
  const size_t rowoff = (size_t)b * NST + jj;

  float alpha = ls[rowoff];  // t = 0

  // prefetch ring: pf[u] holds lsum for step t (consumed 8 steps later)
  float pf[8];
#pragma unroll
  for (int u = 0; u < 8; ++u) pf[u] = ls[(size_t)(1 + u) * LROW + rowoff];

  for (int tb = 1; tb < len; tb += 8) {
#pragma unroll
    for (int u = 0; u < 8; ++u) {
      int t = tb + u;
      if (t < len) {
        float lg = pf[u];
        float tt[9];
#pragma unroll
        for (int i2 = 0; i2 < 9; ++i2)
          tt[i2] = __shfl(alpha, 9 * h9 + i2) + Tcol[i2];
        float ma = fmaxf(fmaxf(tt[0], tt[1]), fmaxf(tt[2], tt[3]));
        float mb = fmaxf(fmaxf(tt[4], tt[5]), fmaxf(tt[6], tt[7]));
        float m9 = fmaxf(fmaxf(ma, mb), tt[8]);
        float s0 = __expf(tt[0] - m9) + __expf(tt[1] - m9);
        float s1 = __expf(tt[2] - m9) + __expf(tt[3] - m9);
        float s2 = __expf(tt[4] - m9) + __expf(tt[5] - m9);
        float s3 = __expf(tt[6] - m9) + __expf(tt[7] - m9);
        float s9 = ((s0 + s1) + (s2 + s3)) + __expf(tt[8] - m9);
        float mo = __shfl_xor(m9, 32);
        float so = __shfl_xor(s9, 32);
        float m  = fmaxf(m9, mo);
        float s  = s9 * __expf(m9 - m) + so * __expf(mo - m);
        alpha = m + __logf(s) + lg;
      }
      int tn = t + 8; if (tn > SEQ - 1) tn = SEQ - 1;   // always in-bounds
      pf[u] = ls[(size_t)tn * LROW + rowoff];
    }
  }

  // log_norm = LSE over states; reduce across lanes (lanes 0..17 valid)
  float v = (lane < NST) ? alpha : -1e30f;
  float mm = v;
#pragma unroll
  for (int d = 32; d; d >>= 1) mm = fmaxf(mm, __shfl_xor(mm, d));
  float e = (lane < NST) ? __expf(alpha - mm) : 0.f;
#pragma unroll
  for (int d = 32; d; d >>= 1) e += __shfl_xor(e, d);
  if (lane == 0) out[b] = ub - (mm + __logf(e));
}

// ---------------- K4: T passthrough (second tuple output) ----------------
__global__ void k_tcopy(const float* __restrict__ Tm, float* __restrict__ out) {
  int i = blockIdx.x * 256 + threadIdx.x;
  if (i < NST * NST) out[BATCH + i] = Tm[i];
}

extern "C" void kernel_launch(void* const* d_in, const int* in_sizes, int n_in,
                              void* d_out, int out_size, void* d_ws, size_t ws_size,
                              hipStream_t stream) {
  const int*   inputs = (const int*)d_in[0];
  const int*   labels = (const int*)d_in[1];
  const float* E      = (const float*)d_in[2];
  const float* Wx_f   = (const float*)d_in[3];
  const float* Wh_f   = (const float*)d_in[4];
  const float* b_f    = (const float*)d_in[5];
  const float* Wx_b   = (const float*)d_in[6];
  const float* Wh_b   = (const float*)d_in[7];
  const float* b_b    = (const float*)d_in[8];
  const float* Wd     = (const float*)d_in[9];
  const float* bd     = (const float*)d_in[10];
  const float* Tm     = (const float*)d_in[11];
  float* out = (float*)d_out;

  char* ws = (char*)d_ws;
  short* emb      = (short*)ws;                                  // 16,777,216 B (dead after k_lstm)
  float* lsum     = (float*)ws;                                  // reuses emb region (9,437,184 B)
  float* logits_f = (float*)(ws + (size_t)16777216);             //  9,437,184 B
  float* logits_b = (float*)(ws + (size_t)16777216 + 9437184);   //  9,437,184 B

  k_embed<<<8192, 256, 0, stream>>>(inputs, E, emb);
  k_lstm<<<128, 512, 0, stream>>>(emb, Wx_f, Wh_f, b_f, Wx_b, Wh_b, b_b, Wd,
                                  logits_f, logits_b);
  k_sum<<<2304, 256, 0, stream>>>(logits_f, logits_b, bd, lsum);
  k_crf<<<128, 256, 0, stream>>>(lsum, Tm, labels, out);
  k_tcopy<<<2, 256, 0, stream>>>(Tm, out);
}

// Round 9
// 329.554 us; speedup vs baseline: 1.3141x; 1.1979x over previous
//
#include <hip/hip_runtime.h>
#include <stdint.h>

#define BATCH 512
#define SEQ   256
#define EMBD  64
#define HID   128
#define GATES 512
#define NST   18
#define LROW  (BATCH * NST)   /* 9216 floats per time slice */

typedef short  bf16x8 __attribute__((ext_vector_type(8)));
typedef float  f32x4  __attribute__((ext_vector_type(4)));

__device__ __forceinline__ short f2bf(float f) {
  unsigned u = __float_as_uint(f);
  u = (u + 0x7FFFu + ((u >> 16) & 1u)) >> 16;
  return (short)u;
}
__device__ __forceinline__ float rcpf(float x) { return __builtin_amdgcn_rcpf(x); }

// lgkm-only barrier (vmem ops stay in flight across it).
__device__ __forceinline__ void lds_barrier() {
  __builtin_amdgcn_sched_barrier(0);
  asm volatile("s_waitcnt lgkmcnt(0)");
  __builtin_amdgcn_s_barrier();
  __builtin_amdgcn_sched_barrier(0);
}

// ---------------- K1: embedding gather, time-major bf16 ----------------
__global__ void k_embed(const int* __restrict__ inputs, const float* __restrict__ E,
                        short* __restrict__ emb) {
  int tid = blockIdx.x * 256 + threadIdx.x;   // 2^21 threads total
  int e4 = (tid & 15) << 2;
  int b  = (tid >> 4) & (BATCH - 1);
  int t  = tid >> 13;
  int vid = inputs[b * SEQ + t];
  float4 v = *reinterpret_cast<const float4*>(E + (size_t)vid * EMBD + e4);
  short4 o;
  o.x = f2bf(v.x); o.y = f2bf(v.y); o.z = f2bf(v.z); o.w = f2bf(v.w);
  *reinterpret_cast<short4*>(emb + (size_t)(t * BATCH + b) * EMBD + e4) = o;
}

// ---------------- K2: bidirectional LSTM + fused logits ----------------
// R9: 256 blocks (all CUs), R=4 batch rows/block, REPLICATED-A trick.
// A-frag row mrow maps to batch row (mrow>>2): the MFMA replicates each
// batch row 4x across the C tile, so lane (quad q, col m) holds its gate-z
// for batch row q in reg 0 directly. Epilogue: 1 element/lane, ZERO
// shuffles (R8's ds_bpermutes doubled bank conflicts and sat in the serial
// chain). h-LDS [4][128] bf16, swizzle ^(row<<5): max 2-way bank aliasing
// (free, m136) for both the 4-lane-broadcast reads and b16 writes.
__global__ void __launch_bounds__(512)
__attribute__((amdgpu_waves_per_eu(2, 2)))
k_lstm(const short* __restrict__ emb,
       const float* __restrict__ Wx_f, const float* __restrict__ Wh_f, const float* __restrict__ b_f,
       const float* __restrict__ Wx_b, const float* __restrict__ Wh_b, const float* __restrict__ b_b,
       const float* __restrict__ Wd,
       float* __restrict__ logits_f, float* __restrict__ logits_b) {
  const int blk  = blockIdx.x;
  const int dir  = blk & 1;
  const int b0   = (blk >> 1) * 4;          // 4 batch rows per block
  const int tid  = threadIdx.x;
  const int w    = tid >> 6;
  const int lane = tid & 63;
  const int quad = lane >> 4;      // 0..3 : k-group for A/B frags, batch row for C
  const int mrow = lane & 15;      // A-frag row / C-frag col
  const int arow = mrow >> 2;      // batch sub-row this lane's A row replicates
  const int hcol = w * 16 + mrow;  // hidden col this lane owns (0..127)
  const int erow = b0 + arow;

  const float* WX = dir ? Wx_b : Wx_f;
  const float* WH = dir ? Wh_b : Wh_f;
  const float* BV = dir ? b_b  : b_f;
  float* LOG = dir ? logits_b : logits_f;

  // ---- load weights into register B-fragments (one-time) ----
  bf16x8 wxf[4][2], whf[4][4], wdf[4];
  float bias[4];
#pragma unroll
  for (int q = 0; q < 4; ++q) {
    int col = q * HID + hcol;
    bias[q] = BV[col];
#pragma unroll
    for (int kt = 0; kt < 2; ++kt) {
      bf16x8 f;
#pragma unroll
      for (int j = 0; j < 8; ++j) {
        int k = kt * 32 + quad * 8 + j;
        f[j] = f2bf(WX[k * GATES + col]);
      }
      wxf[q][kt] = f;
    }
#pragma unroll
    for (int kt = 0; kt < 4; ++kt) {
      bf16x8 f;
#pragma unroll
      for (int j = 0; j < 8; ++j) {
        int k = kt * 32 + quad * 8 + j;
        f[j] = f2bf(WH[k * GATES + col]);
      }
      whf[q][kt] = f;
    }
  }
  const int  lcol = w * 16 + mrow;
  const bool lw   = (w < 2);
  const bool lval = lw && (lcol < NST);
#pragma unroll
  for (int kt = 0; kt < 4; ++kt) {
    bf16x8 f;
#pragma unroll
    for (int j = 0; j < 8; ++j) {
      int k = kt * 32 + quad * 8 + j;
      f[j] = lval ? f2bf(Wd[(dir * HID + k) * NST + lcol]) : (short)0;
    }
    wdf[kt] = f;
  }

  // ---- LDS: double-buffered swizzled h tile [4 rows][128 cols] bf16 ----
  // f(row,col) = (row*256 + 2*col) ^ (row<<5)
  __shared__ __align__(16) short hbuf[2][4 * 128];
  if (tid < 256) {
    int* p = reinterpret_cast<int*>(hbuf);
    p[tid] = 0;   // 256 * 4B == 1024B... need 2048B total
    p[tid + 256] = 0;
  }
  __syncthreads();

  float c = 0.f;
  float la[8];
#pragma unroll
  for (int i = 0; i < 8; ++i) la[i] = 0.f;

  const int t0 = dir ? (SEQ - 1) : 0;
  const short* efp0 = emb + ((size_t)(t0 * BATCH + erow) * EMBD + quad * 8);
  bf16x8 xa0 = *reinterpret_cast<const bf16x8*>(efp0);
  bf16x8 xa1 = *reinterpret_cast<const bf16x8*>(efp0 + 32);

  for (int so = 0; so < SEQ; so += 8) {
#pragma unroll
    for (int si = 0; si < 8; ++si) {
      const int s = so + si;
      const int p = s & 1;
      // prefetch next x fragments
      const int sn = (s + 1 < SEQ) ? s + 1 : s;
      const int tn = dir ? (SEQ - 1 - sn) : sn;
      const short* efp = emb + ((size_t)(tn * BATCH + erow) * EMBD + quad * 8);
      bf16x8 xb0 = *reinterpret_cast<const bf16x8*>(efp);
      bf16x8 xb1 = *reinterpret_cast<const bf16x8*>(efp + 32);

      // h_{s-1} A-fragments (replicated rows): row = arow, k = kt*32+quad*8
      bf16x8 hfr[4];
      const char* hb = reinterpret_cast<const char*>(hbuf[p ^ 1]);
#pragma unroll
      for (int kt = 0; kt < 4; ++kt) {
        unsigned off = (unsigned)(arow * 256 + kt * 64 + quad * 16) ^ ((unsigned)arow << 5);
        hfr[kt] = *reinterpret_cast<const bf16x8*>(hb + off);
      }

      // z = bias + x@Wx + h@Wh ; two independent 3-deep chains per gate
      f32x4 za[4], zb[4];
#pragma unroll
      for (int q = 0; q < 4; ++q) {
        f32x4 a = {bias[q], bias[q], bias[q], bias[q]};
        a = __builtin_amdgcn_mfma_f32_16x16x32_bf16(xa0, wxf[q][0], a, 0, 0, 0);
        f32x4 b2 = {0.f, 0.f, 0.f, 0.f};
        b2 = __builtin_amdgcn_mfma_f32_16x16x32_bf16(xa1, wxf[q][1], b2, 0, 0, 0);
        a  = __builtin_amdgcn_mfma_f32_16x16x32_bf16(hfr[0], whf[q][0], a, 0, 0, 0);
        b2 = __builtin_amdgcn_mfma_f32_16x16x32_bf16(hfr[2], whf[q][2], b2, 0, 0, 0);
        a  = __builtin_amdgcn_mfma_f32_16x16x32_bf16(hfr[1], whf[q][1], a, 0, 0, 0);
        b2 = __builtin_amdgcn_mfma_f32_16x16x32_bf16(hfr[3], whf[q][3], b2, 0, 0, 0);
        za[q] = a; zb[q] = b2;
      }

      // gates: reg 0 holds this lane's (row=quad, col=hcol) z for every gate
      float zi = za[0][0] + zb[0][0];
      float zf = za[1][0] + zb[1][0];
      float zg = za[2][0] + zb[2][0];
      float zo = za[3][0] + zb[3][0];
      float ei  = __expf(-zi);
      float e2g = __expf(-2.f * zg);
      float ef  = __expf(-zf);
      float fg  = rcpf(1.f + ef);
      float it  = (1.f - e2g) * rcpf((1.f + ei) * (1.f + e2g));  // sig(i)*tanh(g)
      float cn  = fg * c + it;
      c = cn;
      float eo  = __expf(-zo);
      float e2c = __expf(-2.f * cn);
      short hv = f2bf((1.f - e2c) * rcpf((1.f + eo) * (1.f + e2c)));  // sig(o)*tanh(c)

      // write h_s: 1 b16 store/lane at f(quad, hcol)
      {
        char* wb = reinterpret_cast<char*>(hbuf[p]);
        unsigned off = (unsigned)(quad * 256 + hcol * 2) ^ ((unsigned)quad << 5);
        *reinterpret_cast<short*>(wb + off) = hv;
      }

      // fused logits for h_{s-1} -> register slot (reg 0 = row quad)
      if (lw && (so + si) > 0) {
        f32x4 l = {0.f, 0.f, 0.f, 0.f};
#pragma unroll
        for (int kt = 0; kt < 4; ++kt)
          l = __builtin_amdgcn_mfma_f32_16x16x32_bf16(hfr[kt], wdf[kt], l, 0, 0, 0);
        la[si] = l[0];
      }

      lds_barrier();   // lgkm-only; x loads + logit stores stay in flight
      xa0 = xb0; xa1 = xb1;
    }

    // flush 8 logit slots (positions so+si-1); vmcnt pays store-acks once
    // per 8 steps instead of every step
    if (lval) {
#pragma unroll
      for (int si = 0; si < 8; ++si) {
        if (so == 0 && si == 0) continue;
        int pos = dir ? (SEQ - so - si) : (so + si - 1);
        LOG[(size_t)pos * LROW + (size_t)(b0 + quad) * NST + lcol] = la[si];
      }
    }
  }

  // final logits for h_{SEQ-1}
  if (lw) {
    const char* hb = reinterpret_cast<const char*>(hbuf[(SEQ - 1) & 1]);
    bf16x8 hfr[4];
#pragma unroll
    for (int kt = 0; kt < 4; ++kt) {
      unsigned off = (unsigned)(arow * 256 + kt * 64 + quad * 16) ^ ((unsigned)arow << 5);
      hfr[kt] = *reinterpret_cast<const bf16x8*>(hb + off);
    }
    f32x4 l = {0.f, 0.f, 0.f, 0.f};
#pragma unroll
    for (int kt = 0; kt < 4; ++kt)
      l = __builtin_amdgcn_mfma_f32_16x16x32_bf16(hfr[kt], wdf[kt], l, 0, 0, 0);
    int tp = dir ? 0 : (SEQ - 1);
    if (lval)
      LOG[(size_t)tp * LROW + (size_t)(b0 + quad) * NST + lcol] = l[0];
  }
}

// ---------------- K3: CRF log-likelihood, one wave per batch row ----------------
// 8-deep raw-load prefetch ring (R6-proven): covers L2/HBM latency in the
// 255-step serial chain. 256 blocks x 2 waves.
__global__ void k_crf(const float* __restrict__ lf, const float* __restrict__ lb,
                      const float* __restrict__ bd, const float* __restrict__ Tm,
                      const int* __restrict__ labels, float* __restrict__ out) {
  const int wv   = threadIdx.x >> 6;
  const int lane = threadIdx.x & 63;
  const int b    = blockIdx.x * 2 + wv;
  __shared__ unsigned char lab[2][SEQ];

  // labels row -> LDS bytes; length = count(label != 0)
  int4 lv = *reinterpret_cast<const int4*>(labels + (size_t)b * SEQ + lane * 4);
  uchar4 lc;
  lc.x = (unsigned char)lv.x; lc.y = (unsigned char)lv.y;
  lc.z = (unsigned char)lv.z; lc.w = (unsigned char)lv.w;
  *reinterpret_cast<uchar4*>(&lab[wv][lane * 4]) = lc;
  int cnt = (lv.x != 0) + (lv.y != 0) + (lv.z != 0) + (lv.w != 0);
#pragma unroll
  for (int d = 32; d; d >>= 1) cnt += __shfl_xor(cnt, d);
  const int len = cnt;

  // unary + binary
  float ub = 0.f;
#pragma unroll
  for (int ii = 0; ii < 4; ++ii) {
    int p = ii * 64 + lane;
    int lp = lab[wv][p];
    if (p < len) {
      size_t o = (size_t)p * LROW + (size_t)b * NST + lp;
      ub += lf[o] + lb[o] + bd[lp];
    }
    if (p < SEQ - 1 && (p + 1) < len)
      ub += Tm[lp * NST + lab[wv][p + 1]];
  }
#pragma unroll
  for (int d = 32; d; d >>= 1) ub += __shfl_xor(ub, d);

  // forward algorithm. h9 = lane>>5 (9-state half), j = lane&31 (state).
  const int h9 = lane >> 5;
  const int j  = lane & 31;
  const int jj = (j < NST) ? j : 0;
  float Tcol[9];
#pragma unroll
  for (int i2 = 0; i2 < 9; ++i2) Tcol[i2] = Tm[(9 * h9 + i2) * NST + jj];
  const float bdj = bd[jj];
  const size_t rowoff = (size_t)b * NST + jj;

  float alpha = lf[rowoff] + lb[rowoff] + bdj;  // t = 0

  // prefetch ring: pfa/pfb[u] hold raw lf/lb for step t (consumed 8 later)
  float pfa[8], pfb[8];
#pragma unroll
  for (int u = 0; u < 8; ++u) {
    size_t o = (size_t)(1 + u) * LROW + rowoff;
    pfa[u] = lf[o]; pfb[u] = lb[o];
  }

  for (int tb = 1; tb < len; tb += 8) {
#pragma unroll
    for (int u = 0; u < 8; ++u) {
      int t = tb + u;
      if (t < len) {
        float lg = pfa[u] + pfb[u] + bdj;
        float tt[9];
#pragma unroll
        for (int i2 = 0; i2 < 9; ++i2)
          tt[i2] = __shfl(alpha, 9 * h9 + i2) + Tcol[i2];
        float ma = fmaxf(fmaxf(tt[0], tt[1]), fmaxf(tt[2], tt[3]));
        float mb = fmaxf(fmaxf(tt[4], tt[5]), fmaxf(tt[6], tt[7]));
        float m9 = fmaxf(fmaxf(ma, mb), tt[8]);
        float s0 = __expf(tt[0] - m9) + __expf(tt[1] - m9);
        float s1 = __expf(tt[2] - m9) + __expf(tt[3] - m9);
        float s2 = __expf(tt[4] - m9) + __expf(tt[5] - m9);
        float s3 = __expf(tt[6] - m9) + __expf(tt[7] - m9);
        float s9 = ((s0 + s1) + (s2 + s3)) + __expf(tt[8] - m9);
        float mo = __shfl_xor(m9, 32);
        float so = __shfl_xor(s9, 32);
        float m  = fmaxf(m9, mo);
        float s  = s9 * __expf(m9 - m) + so * __expf(mo - m);
        alpha = m + __logf(s) + lg;
      }
      int tn = t + 8; if (tn > SEQ - 1) tn = SEQ - 1;   // always in-bounds
      size_t o = (size_t)tn * LROW + rowoff;
      pfa[u] = lf[o]; pfb[u] = lb[o];
    }
  }

  // log_norm = LSE over states; reduce across lanes (lanes 0..17 valid)
  float v = (lane < NST) ? alpha : -1e30f;
  float mm = v;
#pragma unroll
  for (int d = 32; d; d >>= 1) mm = fmaxf(mm, __shfl_xor(mm, d));
  float e = (lane < NST) ? __expf(alpha - mm) : 0.f;
#pragma unroll
  for (int d = 32; d; d >>= 1) e += __shfl_xor(e, d);
  if (lane == 0) out[b] = ub - (mm + __logf(e));
}

// ---------------- K4: T passthrough (second tuple output) ----------------
__global__ void k_tcopy(const float* __restrict__ Tm, float* __restrict__ out) {
  int i = blockIdx.x * 256 + threadIdx.x;
  if (i < NST * NST) out[BATCH + i] = Tm[i];
}

extern "C" void kernel_launch(void* const* d_in, const int* in_sizes, int n_in,
                              void* d_out, int out_size, void* d_ws, size_t ws_size,
                              hipStream_t stream) {
  const int*   inputs = (const int*)d_in[0];
  const int*   labels = (const int*)d_in[1];
  const float* E      = (const float*)d_in[2];
  const float* Wx_f   = (const float*)d_in[3];
  const float* Wh_f   = (const float*)d_in[4];
  const float* b_f    = (const float*)d_in[5];
  const float* Wx_b   = (const float*)d_in[6];
  const float* Wh_b   = (const float*)d_in[7];
  const float* b_b    = (const float*)d_in[8];
  const float* Wd     = (const float*)d_in[9];
  const float* bd     = (const float*)d_in[10];
  const float* Tm     = (const float*)d_in[11];
  float* out = (float*)d_out;

  char* ws = (char*)d_ws;
  short* emb      = (short*)ws;                                  // 16,777,216 B
  float* logits_f = (float*)(ws + (size_t)16777216);             //  9,437,184 B
  float* logits_b = (float*)(ws + (size_t)16777216 + 9437184);   //  9,437,184 B

  k_embed<<<8192, 256, 0, stream>>>(inputs, E, emb);
  k_lstm<<<256, 512, 0, stream>>>(emb, Wx_f, Wh_f, b_f, Wx_b, Wh_b, b_b, Wd,
                                  logits_f, logits_b);
  k_crf<<<256, 128, 0, stream>>>(logits_f, logits_b, bd, Tm, labels, out);
  k_tcopy<<<2, 256, 0, stream>>>(Tm, out);
}

// Round 11
// 296.048 us; speedup vs baseline: 1.4629x; 1.1132x over previous
//
#include <hip/hip_runtime.h>
#include <stdint.h>

#define BATCH 512
#define SEQ   256
#define EMBD  64
#define HID   128
#define GATES 512
#define NST   18
#define LROW  (BATCH * NST)   /* 9216 floats per time slice */

typedef short  bf16x8 __attribute__((ext_vector_type(8)));
typedef float  f32x4  __attribute__((ext_vector_type(4)));

__device__ __forceinline__ short f2bf(float f) {
  unsigned u = __float_as_uint(f);
  u = (u + 0x7FFFu + ((u >> 16) & 1u)) >> 16;
  return (short)u;
}
__device__ __forceinline__ float rcpf(float x) { return __builtin_amdgcn_rcpf(x); }

// lgkm-only barrier (vmem ops stay in flight across it).
__device__ __forceinline__ void lds_barrier() {
  __builtin_amdgcn_sched_barrier(0);
  asm volatile("s_waitcnt lgkmcnt(0)");
  __builtin_amdgcn_s_barrier();
  __builtin_amdgcn_sched_barrier(0);
}

// ---------------- K1: embedding gather, time-major bf16 ----------------
__global__ void k_embed(const int* __restrict__ inputs, const float* __restrict__ E,
                        short* __restrict__ emb) {
  int tid = blockIdx.x * 256 + threadIdx.x;   // 2^21 threads total
  int e4 = (tid & 15) << 2;
  int b  = (tid >> 4) & (BATCH - 1);
  int t  = tid >> 13;
  int vid = inputs[b * SEQ + t];
  float4 v = *reinterpret_cast<const float4*>(E + (size_t)vid * EMBD + e4);
  short4 o;
  o.x = f2bf(v.x); o.y = f2bf(v.y); o.z = f2bf(v.z); o.w = f2bf(v.w);
  *reinterpret_cast<short4*>(emb + (size_t)(t * BATCH + b) * EMBD + e4) = o;
}

// ---------------- K2: bidirectional LSTM + fused logits ----------------
// R9 structure (256 blocks, R=4, replicated-A, zero shuffles) + R10:
// persistent accumulators with ELEMENT-0-ONLY re-init. MFMA C-out[r] depends
// only on C-in[r], so garbage in elements 1-3 is harmless (linear growth,
// never read). 8 v_movs/step instead of 32.
__global__ void __launch_bounds__(512)
__attribute__((amdgpu_waves_per_eu(2, 2)))
k_lstm(const short* __restrict__ emb,
       const float* __restrict__ Wx_f, const float* __restrict__ Wh_f, const float* __restrict__ b_f,
       const float* __restrict__ Wx_b, const float* __restrict__ Wh_b, const float* __restrict__ b_b,
       const float* __restrict__ Wd,
       float* __restrict__ logits_f, float* __restrict__ logits_b) {
  const int blk  = blockIdx.x;
  const int dir  = blk & 1;
  const int b0   = (blk >> 1) * 4;          // 4 batch rows per block
  const int tid  = threadIdx.x;
  const int w    = tid >> 6;
  const int lane = tid & 63;
  const int quad = lane >> 4;      // 0..3 : k-group for A/B frags, batch row for C
  const int mrow = lane & 15;      // A-frag row / C-frag col
  const int arow = mrow >> 2;      // batch sub-row this lane's A row replicates
  const int hcol = w * 16 + mrow;  // hidden col this lane owns (0..127)
  const int erow = b0 + arow;

  const float* WX = dir ? Wx_b : Wx_f;
  const float* WH = dir ? Wh_b : Wh_f;
  const float* BV = dir ? b_b  : b_f;
  float* LOG = dir ? logits_b : logits_f;

  // ---- load weights into register B-fragments (one-time) ----
  bf16x8 wxf[4][2], whf[4][4], wdf[4];
  float bias[4];
#pragma unroll
  for (int q = 0; q < 4; ++q) {
    int col = q * HID + hcol;
    bias[q] = BV[col];
#pragma unroll
    for (int kt = 0; kt < 2; ++kt) {
      bf16x8 f;
#pragma unroll
      for (int j = 0; j < 8; ++j) {
        int k = kt * 32 + quad * 8 + j;
        f[j] = f2bf(WX[k * GATES + col]);
      }
      wxf[q][kt] = f;
    }
#pragma unroll
    for (int kt = 0; kt < 4; ++kt) {
      bf16x8 f;
#pragma unroll
      for (int j = 0; j < 8; ++j) {
        int k = kt * 32 + quad * 8 + j;
        f[j] = f2bf(WH[k * GATES + col]);
      }
      whf[q][kt] = f;
    }
  }
  const int  lcol = w * 16 + mrow;
  const bool lw   = (w < 2);
  const bool lval = lw && (lcol < NST);
#pragma unroll
  for (int kt = 0; kt < 4; ++kt) {
    bf16x8 f;
#pragma unroll
    for (int j = 0; j < 8; ++j) {
      int k = kt * 32 + quad * 8 + j;
      f[j] = lval ? f2bf(Wd[(dir * HID + k) * NST + lcol]) : (short)0;
    }
    wdf[kt] = f;
  }

  // ---- LDS: double-buffered swizzled h tile [4 rows][128 cols] bf16 ----
  // f(row,col) = (row*256 + 2*col) ^ (row<<5)
  __shared__ __align__(16) short hbuf[2][4 * 128];
  if (tid < 256) {
    int* p = reinterpret_cast<int*>(hbuf);
    p[tid] = 0;
    p[tid + 256] = 0;
  }
  __syncthreads();

  float c = 0.f;
  float la[8];
#pragma unroll
  for (int i = 0; i < 8; ++i) la[i] = 0.f;

  // persistent accumulators; only element 0 re-armed per step
  f32x4 za[4], zb[4], lacc;
#pragma unroll
  for (int q = 0; q < 4; ++q) {
    za[q][0] = 0.f; za[q][1] = 0.f; za[q][2] = 0.f; za[q][3] = 0.f;
    zb[q] = za[q];
  }
  lacc[0] = 0.f; lacc[1] = 0.f; lacc[2] = 0.f; lacc[3] = 0.f;

  const int t0 = dir ? (SEQ - 1) : 0;
  const short* efp0 = emb + ((size_t)(t0 * BATCH + erow) * EMBD + quad * 8);
  bf16x8 xa0 = *reinterpret_cast<const bf16x8*>(efp0);
  bf16x8 xa1 = *reinterpret_cast<const bf16x8*>(efp0 + 32);

  for (int so = 0; so < SEQ; so += 8) {
#pragma unroll
    for (int si = 0; si < 8; ++si) {
      const int s = so + si;
      const int p = s & 1;
      // prefetch next x fragments
      const int sn = (s + 1 < SEQ) ? s + 1 : s;
      const int tn = dir ? (SEQ - 1 - sn) : sn;
      const short* efp = emb + ((size_t)(tn * BATCH + erow) * EMBD + quad * 8);
      bf16x8 xb0 = *reinterpret_cast<const bf16x8*>(efp);
      bf16x8 xb1 = *reinterpret_cast<const bf16x8*>(efp + 32);

      // h_{s-1} A-fragments (replicated rows): row = arow, k = kt*32+quad*8
      bf16x8 hfr[4];
      const char* hb = reinterpret_cast<const char*>(hbuf[p ^ 1]);
#pragma unroll
      for (int kt = 0; kt < 4; ++kt) {
        unsigned off = (unsigned)(arow * 256 + kt * 64 + quad * 16) ^ ((unsigned)arow << 5);
        hfr[kt] = *reinterpret_cast<const bf16x8*>(hb + off);
      }

      // z = bias + x@Wx + h@Wh ; two independent 3-deep chains per gate.
      // element-0-only re-init (elements 1-3 keep harmless garbage)
#pragma unroll
      for (int q = 0; q < 4; ++q) {
        za[q][0] = bias[q];
        zb[q][0] = 0.f;
        za[q] = __builtin_amdgcn_mfma_f32_16x16x32_bf16(xa0, wxf[q][0], za[q], 0, 0, 0);
        zb[q] = __builtin_amdgcn_mfma_f32_16x16x32_bf16(xa1, wxf[q][1], zb[q], 0, 0, 0);
        za[q] = __builtin_amdgcn_mfma_f32_16x16x32_bf16(hfr[0], whf[q][0], za[q], 0, 0, 0);
        zb[q] = __builtin_amdgcn_mfma_f32_16x16x32_bf16(hfr[2], whf[q][2], zb[q], 0, 0, 0);
        za[q] = __builtin_amdgcn_mfma_f32_16x16x32_bf16(hfr[1], whf[q][1], za[q], 0, 0, 0);
        zb[q] = __builtin_amdgcn_mfma_f32_16x16x32_bf16(hfr[3], whf[q][3], zb[q], 0, 0, 0);
      }

      // gates: element 0 holds this lane's (row=quad, col=hcol) z
      float zi = za[0][0] + zb[0][0];
      float zf = za[1][0] + zb[1][0];
      float zg = za[2][0] + zb[2][0];
      float zo = za[3][0] + zb[3][0];
      float ei  = __expf(-zi);
      float e2g = __expf(-2.f * zg);
      float ef  = __expf(-zf);
      float fg  = rcpf(1.f + ef);
      float it  = (1.f - e2g) * rcpf((1.f + ei) * (1.f + e2g));  // sig(i)*tanh(g)
      float cn  = fg * c + it;
      c = cn;
      float eo  = __expf(-zo);
      float e2c = __expf(-2.f * cn);
      short hv = f2bf((1.f - e2c) * rcpf((1.f + eo) * (1.f + e2c)));  // sig(o)*tanh(c)

      // write h_s: 1 b16 store/lane at f(quad, hcol)
      {
        char* wb = reinterpret_cast<char*>(hbuf[p]);
        unsigned off = (unsigned)(quad * 256 + hcol * 2) ^ ((unsigned)quad << 5);
        *reinterpret_cast<short*>(wb + off) = hv;
      }

      // fused logits for h_{s-1} -> register slot (element 0 = row quad)
      if (lw && (so + si) > 0) {
        lacc[0] = 0.f;
#pragma unroll
        for (int kt = 0; kt < 4; ++kt)
          lacc = __builtin_amdgcn_mfma_f32_16x16x32_bf16(hfr[kt], wdf[kt], lacc, 0, 0, 0);
        la[si] = lacc[0];
      }

      lds_barrier();   // lgkm-only; x loads + logit stores stay in flight
      xa0 = xb0; xa1 = xb1;
    }

    // flush 8 logit slots (positions so+si-1)
    if (lval) {
#pragma unroll
      for (int si = 0; si < 8; ++si) {
        if (so == 0 && si == 0) continue;
        int pos = dir ? (SEQ - so - si) : (so + si - 1);
        LOG[(size_t)pos * LROW + (size_t)(b0 + quad) * NST + lcol] = la[si];
      }
    }
  }

  // final logits for h_{SEQ-1}
  if (lw) {
    const char* hb = reinterpret_cast<const char*>(hbuf[(SEQ - 1) & 1]);
    bf16x8 hfr[4];
#pragma unroll
    for (int kt = 0; kt < 4; ++kt) {
      unsigned off = (unsigned)(arow * 256 + kt * 64 + quad * 16) ^ ((unsigned)arow << 5);
      hfr[kt] = *reinterpret_cast<const bf16x8*>(hb + off);
    }
    lacc[0] = 0.f;
#pragma unroll
    for (int kt = 0; kt < 4; ++kt)
      lacc = __builtin_amdgcn_mfma_f32_16x16x32_bf16(hfr[kt], wdf[kt], lacc, 0, 0, 0);
    int tp = dir ? 0 : (SEQ - 1);
    if (lval)
      LOG[(size_t)tp * LROW + (size_t)(b0 + quad) * NST + lcol] = lacc[0];
  }
}

// ---------------- K3: CRF log-likelihood, forward/backward split ----------------
// logZ = LSE_i(alpha_tm[i] + beta_tm[i]) for ANY tm (exact). Wave pair per row:
// even wave runs forward alpha to tm=(len-1)/2 (+ unary/binary), odd wave runs
// backward beta_t[i] = LSE_j(T[i][j] + lg_{t+1}[j] + beta_{t+1}[j]) down to tm.
// Halves the 255-step serial chain AND doubles resident waves (1/SIMD on all
// 256 CUs). 8-deep raw-load prefetch rings on both sides.
__global__ void k_crf(const float* __restrict__ lf, const float* __restrict__ lb,
                      const float* __restrict__ bd, const float* __restrict__ Tm,
                      const int* __restrict__ labels, float* __restrict__ out) {
  const int wv    = threadIdx.x >> 6;     // 0..3
  const int rsel  = wv >> 1;              // row slot in block
  const int isBwd = wv & 1;
  const int lane  = threadIdx.x & 63;
  const int b     = blockIdx.x * 2 + rsel;
  __shared__ unsigned char lab[2][SEQ];
  __shared__ float redA[2][NST], redB[2][NST], ubv[2];

  // labels -> len (each wave computes from its own loads)
  int4 lv = *reinterpret_cast<const int4*>(labels + (size_t)b * SEQ + lane * 4);
  int cnt = (lv.x != 0) + (lv.y != 0) + (lv.z != 0) + (lv.w != 0);
#pragma unroll
  for (int d = 32; d; d >>= 1) cnt += __shfl_xor(cnt, d);
  const int len = cnt;
  const int tm  = (len - 1) >> 1;

  const int h9 = lane >> 5;
  const int j  = lane & 31;
  const int jj = (j < NST) ? j : 0;
  const float bdj = bd[jj];
  const size_t rowoff = (size_t)b * NST + jj;

  if (!isBwd) {
    // ---- labels to LDS (only fwd wave) + unary/binary ----
    uchar4 lc;
    lc.x = (unsigned char)lv.x; lc.y = (unsigned char)lv.y;
    lc.z = (unsigned char)lv.z; lc.w = (unsigned char)lv.w;
    *reinterpret_cast<uchar4*>(&lab[rsel][lane * 4]) = lc;
    float ub = 0.f;
#pragma unroll
    for (int ii = 0; ii < 4; ++ii) {
      int p = ii * 64 + lane;
      int lp = lab[rsel][p];
      if (p < len) {
        size_t o = (size_t)p * LROW + (size_t)b * NST + lp;
        ub += lf[o] + lb[o] + bd[lp];
      }
      if (p < SEQ - 1 && (p + 1) < len)
        ub += Tm[lp * NST + lab[rsel][p + 1]];
    }
#pragma unroll
    for (int d = 32; d; d >>= 1) ub += __shfl_xor(ub, d);
    if (lane == 0) ubv[rsel] = ub;

    // ---- forward alpha to tm ----
    float Tcol[9];
#pragma unroll
    for (int i2 = 0; i2 < 9; ++i2) Tcol[i2] = Tm[(9 * h9 + i2) * NST + jj];
    float alpha = lf[rowoff] + lb[rowoff] + bdj;  // t = 0
    float pfa[8], pfb[8];
#pragma unroll
    for (int u = 0; u < 8; ++u) {
      int ti = 1 + u; if (ti > SEQ - 1) ti = SEQ - 1;
      size_t o = (size_t)ti * LROW + rowoff;
      pfa[u] = lf[o]; pfb[u] = lb[o];
    }
    for (int tb = 1; tb <= tm; tb += 8) {
#pragma unroll
      for (int u = 0; u < 8; ++u) {
        int t = tb + u;
        if (t <= tm) {
          float lg = pfa[u] + pfb[u] + bdj;
          float tt[9];
#pragma unroll
          for (int i2 = 0; i2 < 9; ++i2)
            tt[i2] = __shfl(alpha, 9 * h9 + i2) + Tcol[i2];
          float ma = fmaxf(fmaxf(tt[0], tt[1]), fmaxf(tt[2], tt[3]));
          float mb = fmaxf(fmaxf(tt[4], tt[5]), fmaxf(tt[6], tt[7]));
          float m9 = fmaxf(fmaxf(ma, mb), tt[8]);
          float s0 = __expf(tt[0] - m9) + __expf(tt[1] - m9);
          float s1 = __expf(tt[2] - m9) + __expf(tt[3] - m9);
          float s2 = __expf(tt[4] - m9) + __expf(tt[5] - m9);
          float s3 = __expf(tt[6] - m9) + __expf(tt[7] - m9);
          float s9 = ((s0 + s1) + (s2 + s3)) + __expf(tt[8] - m9);
          float mo = __shfl_xor(m9, 32);
          float so = __shfl_xor(s9, 32);
          float m  = fmaxf(m9, mo);
          float s  = s9 * __expf(m9 - m) + so * __expf(mo - m);
          alpha = m + __logf(s) + lg;
        }
        int ti = t + 8; if (ti > SEQ - 1) ti = SEQ - 1;
        size_t o = (size_t)ti * LROW + rowoff;
        pfa[u] = lf[o]; pfb[u] = lb[o];
      }
    }
    if (lane < NST) redA[rsel][lane] = alpha;
  } else {
    // ---- backward beta from len-1 down to tm ----
    float Trow[9];
#pragma unroll
    for (int i2 = 0; i2 < 9; ++i2) Trow[i2] = Tm[jj * NST + 9 * h9 + i2];
    float beta = 0.f;
    // step t consumes lg_{t+1}; t descends len-2 .. tm
    float pfa[8], pfb[8];
#pragma unroll
    for (int u = 0; u < 8; ++u) {
      int ti = len - 1 - u; if (ti < 0) ti = 0;
      size_t o = (size_t)ti * LROW + rowoff;
      pfa[u] = lf[o]; pfb[u] = lb[o];
    }
    for (int tb = len - 2; tb >= tm; tb -= 8) {
#pragma unroll
      for (int u = 0; u < 8; ++u) {
        int t = tb - u;
        if (t >= tm) {
          float gj = beta + (pfa[u] + pfb[u] + bdj);  // gamma[j]=beta[j]+lg_{t+1}[j]
          float tt[9];
#pragma unroll
          for (int i2 = 0; i2 < 9; ++i2)
            tt[i2] = __shfl(gj, 9 * h9 + i2) + Trow[i2];
          float ma = fmaxf(fmaxf(tt[0], tt[1]), fmaxf(tt[2], tt[3]));
          float mb = fmaxf(fmaxf(tt[4], tt[5]), fmaxf(tt[6], tt[7]));
          float m9 = fmaxf(fmaxf(ma, mb), tt[8]);
          float s0 = __expf(tt[0] - m9) + __expf(tt[1] - m9);
          float s1 = __expf(tt[2] - m9) + __expf(tt[3] - m9);
          float s2 = __expf(tt[4] - m9) + __expf(tt[5] - m9);
          float s3 = __expf(tt[6] - m9) + __expf(tt[7] - m9);
          float s9 = ((s0 + s1) + (s2 + s3)) + __expf(tt[8] - m9);
          float mo = __shfl_xor(m9, 32);
          float so = __shfl_xor(s9, 32);
          float m  = fmaxf(m9, mo);
          float s  = s9 * __expf(m9 - m) + so * __expf(mo - m);
          beta = m + __logf(s);
        }
        int ti = t + 1 - 8; if (ti < 0) ti = 0;
        size_t o = (size_t)ti * LROW + rowoff;
        pfa[u] = lf[o]; pfb[u] = lb[o];
      }
    }
    if (lane < NST) redB[rsel][lane] = beta;
  }

  __syncthreads();

  // combine: logZ = LSE(alpha_tm + beta_tm); out = ub - logZ
  if (wv < 2) {
    float v = (lane < NST) ? redA[wv][lane] + redB[wv][lane] : -1e30f;
    float mm = v;
#pragma unroll
    for (int d = 32; d; d >>= 1) mm = fmaxf(mm, __shfl_xor(mm, d));
    float e = (lane < NST) ? __expf(v - mm) : 0.f;
#pragma unroll
    for (int d = 32; d; d >>= 1) e += __shfl_xor(e, d);
    if (lane == 0) out[blockIdx.x * 2 + wv] = ubv[wv] - (mm + __logf(e));
  }
}

// ---------------- K4: T passthrough (second tuple output) ----------------
__global__ void k_tcopy(const float* __restrict__ Tm, float* __restrict__ out) {
  int i = blockIdx.x * 256 + threadIdx.x;
  if (i < NST * NST) out[BATCH + i] = Tm[i];
}

extern "C" void kernel_launch(void* const* d_in, const int* in_sizes, int n_in,
                              void* d_out, int out_size, void* d_ws, size_t ws_size,
                              hipStream_t stream) {
  const int*   inputs = (const int*)d_in[0];
  const int*   labels = (const int*)d_in[1];
  const float* E      = (const float*)d_in[2];
  const float* Wx_f   = (const float*)d_in[3];
  const float* Wh_f   = (const float*)d_in[4];
  const float* b_f    = (const float*)d_in[5];
  const float* Wx_b   = (const float*)d_in[6];
  const float* Wh_b   = (const float*)d_in[7];
  const float* b_b    = (const float*)d_in[8];
  const float* Wd     = (const float*)d_in[9];
  const float* bd     = (const float*)d_in[10];
  const float* Tm     = (const float*)d_in[11];
  float* out = (float*)d_out;

  char* ws = (char*)d_ws;
  short* emb      = (short*)ws;                                  // 16,777,216 B
  float* logits_f = (float*)(ws + (size_t)16777216);             //  9,437,184 B
  float* logits_b = (float*)(ws + (size_t)16777216 + 9437184);   //  9,437,184 B

  k_embed<<<8192, 256, 0, stream>>>(inputs, E, emb);
  k_lstm<<<256, 512, 0, stream>>>(emb, Wx_f, Wh_f, b_f, Wx_b, Wh_b, b_b, Wd,
                                  logits_f, logits_b);
  k_crf<<<256, 256, 0, stream>>>(logits_f, logits_b, bd, Tm, labels, out);
  k_tcopy<<<2, 256, 0, stream>>>(Tm, out);
}